// Round 8
// baseline (982.411 us; speedup 1.0000x reference)
//
#include <hip/hip_runtime.h>
#include <hip/hip_bf16.h>

typedef float  f32x4  __attribute__((ext_vector_type(4)));
typedef short  short4v __attribute__((ext_vector_type(4)));
typedef short  short8v __attribute__((ext_vector_type(8)));

#define DIM   256
#define BM2   64          // rows per block (main kernel)
#define NT2   256
#define EPS   0.05f
#define RB    2048
#define GB    1024

__device__ __forceinline__ ushort bf16rn(float f) {
  union { float f; uint u; } x; x.f = f;
  const uint u = x.u;
  return (ushort)((u + 0x7fffu + ((u >> 16) & 1u)) >> 16);
}
__device__ __forceinline__ float bf16tof(ushort h) {
  union { uint u; float f; } x; x.u = ((uint)h) << 16; return x.f;
}

// ||c_k||^2 in f64 (+ f32 copy) AND pre-split codebook to bf16 hi/lo.
__global__ __launch_bounds__(64) void vq_cnorm(const float* __restrict__ cb,
                                               double* __restrict__ cn2,
                                               float* __restrict__ cnf,
                                               ushort* __restrict__ cbh,
                                               ushort* __restrict__ cbl) {
  const int k    = blockIdx.x;
  const int lane = threadIdx.x;
  const f32x4 v = ((const f32x4*)(cb + (size_t)k * DIM))[lane];
  short4v h, lo;
  #pragma unroll
  for (int e = 0; e < 4; ++e) {
    const ushort hb = bf16rn(v[e]);
    h[e]  = (short)hb;
    lo[e] = (short)bf16rn(v[e] - bf16tof(hb));
  }
  *(short4v*)(cbh + (size_t)k * DIM + lane * 4) = h;
  *(short4v*)(cbl + (size_t)k * DIM + lane * 4) = lo;
  double s = (double)v[0]*v[0] + (double)v[1]*v[1] +
             (double)v[2]*v[2] + (double)v[3]*v[3];
  for (int off = 32; off; off >>= 1) s += __shfl_down(s, off, 64);
  if (lane == 0) { cn2[k] = s; cnf[k] = (float)s; }
}

// Main: persistent z hi/lo in LDS, barrier-free chunk loop, B from L2.
__global__ __launch_bounds__(NT2, 2) void vq_mfma2(const float* __restrict__ z,
                                                   const ushort* __restrict__ cbh,
                                                   const ushort* __restrict__ cbl,
                                                   const float* __restrict__ cnf,
                                                   float* __restrict__ idx_out) {
  __shared__ __align__(16) ushort zhS[BM2 * DIM];   // 32 KB
  __shared__ __align__(16) ushort zlS[BM2 * DIM];   // 32 KB
  __shared__ float cns[1024];
  __shared__ float rb1[2][BM2];
  __shared__ float rb2[2][BM2];
  __shared__ int   ri1[2][BM2];

  char* zhB = (char*)zhS; char* zlB = (char*)zlS;
  const char* cbhB = (const char*)cbh;
  const char* cblB = (const char*)cbl;

  const int t  = threadIdx.x;
  const int l  = t & 63, w = t >> 6;
  const int wm = w >> 1, wn = w & 1;          // wave tile: 32 rows x 64 codes
  const int lr = l & 15, lg = l >> 4;
  const size_t rbase = (size_t)blockIdx.x * BM2;

  for (int i = t; i < 1024; i += NT2) cns[i] = cnf[i];

  // stage z tile once: 64 rows x 256 dims -> bf16 hi/lo, XOR-swizzled
  {
    const f32x4* zg4 = (const f32x4*)z;
    for (int i = t; i < BM2 * 64; i += NT2) {
      const int r = i >> 6, c = i & 63;
      const f32x4 vz = zg4[(rbase + r) * 64 + c];
      short4v hz, lz;
      #pragma unroll
      for (int e = 0; e < 4; ++e) {
        const ushort hb = bf16rn(vz[e]);
        hz[e] = (short)hb;
        lz[e] = (short)bf16rn(vz[e] - bf16tof(hb));
      }
      const uint off = ((uint)(r * 512 + c * 8)) ^ ((uint)(r & 7) << 4);
      *(short4v*)(zhB + off) = hz;
      *(short4v*)(zlB + off) = lz;
    }
  }
  __syncthreads();

  float b1[8], b2[8]; int i1[8];
  #pragma unroll
  for (int s = 0; s < 8; ++s) { b1[s] = 3.0e38f; b2[s] = 3.0e38f; i1[s] = 0; }

  for (int chunk = 0; chunk < 8; ++chunk) {
    f32x4 acc[2][4];
    #pragma unroll
    for (int m = 0; m < 2; ++m)
      #pragma unroll
      for (int n = 0; n < 4; ++n) acc[m][n] = (f32x4){0.f, 0.f, 0.f, 0.f};

    #pragma unroll
    for (int s = 0; s < 8; ++s) {            // 8 k-steps of 32 dims
      short8v ah[2], al_[2];
      #pragma unroll
      for (int m = 0; m < 2; ++m) {
        const int r = wm * 32 + m * 16 + lr;
        const uint off = ((uint)(r * 512 + s * 64 + lg * 16)) ^ ((uint)(r & 7) << 4);
        ah[m]  = *(const short8v*)(zhB + off);
        al_[m] = *(const short8v*)(zlB + off);
      }
      short8v bh[4], bl_[4];
      #pragma unroll
      for (int n = 0; n < 4; ++n) {
        const uint code = (uint)(chunk * 128 + wn * 64 + n * 16 + lr);
        const uint goff = code * 512 + (uint)(s * 64 + lg * 16);
        bh[n]  = *(const short8v*)(cbhB + goff);
        bl_[n] = *(const short8v*)(cblB + goff);
      }
      #pragma unroll
      for (int m = 0; m < 2; ++m)
        #pragma unroll
        for (int n = 0; n < 4; ++n) {
          acc[m][n] = __builtin_amdgcn_mfma_f32_16x16x32_bf16(ah[m],  bh[n],  acc[m][n], 0, 0, 0);
          acc[m][n] = __builtin_amdgcn_mfma_f32_16x16x32_bf16(ah[m],  bl_[n], acc[m][n], 0, 0, 0);
          acc[m][n] = __builtin_amdgcn_mfma_f32_16x16x32_bf16(al_[m], bh[n],  acc[m][n], 0, 0, 0);
        }
    }

    // epilogue: dd = ||c||^2 - 2 dot ; best/second update (codes ascend)
    #pragma unroll
    for (int n = 0; n < 4; ++n) {
      const int cg = chunk * 128 + wn * 64 + n * 16 + lr;
      const float cn = cns[cg];
      #pragma unroll
      for (int m = 0; m < 2; ++m)
        #pragma unroll
        for (int r = 0; r < 4; ++r) {
          const float dd = fmaf(-2.0f, acc[m][n][r], cn);
          const int s = m * 4 + r;
          const bool lt = dd < b1[s];
          b2[s] = lt ? b1[s] : fminf(b2[s], dd);
          i1[s] = lt ? cg : i1[s];
          b1[s] = lt ? dd : b1[s];
        }
    }
  }

  // merge across the 16 lanes (lr) sharing the same rows
  #pragma unroll
  for (int s = 0; s < 8; ++s) {
    #pragma unroll
    for (int off = 1; off < 16; off <<= 1) {
      const float ob1 = __shfl_xor(b1[s], off, 16);
      const float ob2 = __shfl_xor(b2[s], off, 16);
      const int   oi  = __shfl_xor(i1[s], off, 16);
      const float hi  = fmaxf(b1[s], ob1);
      b2[s] = fminf(fminf(b2[s], ob2), hi);
      if (ob1 < b1[s] || (ob1 == b1[s] && oi < i1[s])) { b1[s] = ob1; i1[s] = oi; }
    }
  }
  if (lr == 0) {
    #pragma unroll
    for (int m = 0; m < 2; ++m)
      #pragma unroll
      for (int r = 0; r < 4; ++r) {
        const int s = m * 4 + r;
        const int row = wm * 32 + m * 16 + lg * 4 + r;
        rb1[wn][row] = b1[s]; rb2[wn][row] = b2[s]; ri1[wn][row] = i1[s];
      }
  }
  __syncthreads();
  if (t < BM2) {
    const float a1 = rb1[0][t], a2 = rb2[0][t]; const int ai = ri1[0][t];
    const float c1 = rb1[1][t], c2 = rb2[1][t]; const int ci = ri1[1][t];
    const float m2 = fminf(fminf(a2, c2), fmaxf(a1, c1));
    float m1; int mi;
    if (c1 < a1 || (c1 == a1 && ci < ai)) { m1 = c1; mi = ci; } else { m1 = a1; mi = ai; }
    idx_out[rbase + t] = (m2 - m1 > EPS) ? (float)mi : -1.0f;
  }
}

// Exact f64 re-check for sentinel rows
__global__ __launch_bounds__(256) void vq_recheck(const float* __restrict__ z,
                                                  const float* __restrict__ cb,
                                                  const double* __restrict__ cn2,
                                                  float* __restrict__ idx_out, int N) {
  __shared__ __align__(16) float zrow[DIM];
  __shared__ __align__(16) float cbs[32*DIM];
  __shared__ double bls[32];
  __shared__ int    bis[32];
  const int t = threadIdx.x;
  for (int row = blockIdx.x; row < N; row += RB) {
    const float f = idx_out[row];
    if (f >= 0.0f) continue;
    if (t < 64) ((f32x4*)zrow)[t] = ((const f32x4*)z)[(size_t)row*64 + t];
    double best = 1.0e300; int bidx = 0;
    for (int ch = 0; ch < 32; ++ch) {
      __syncthreads();
      #pragma unroll
      for (int i = 0; i < 8; ++i)
        ((f32x4*)cbs)[t + i*256] = ((const f32x4*)cb)[(size_t)ch*2048 + t + i*256];
      __syncthreads();
      const float* cr = cbs  + (t >> 3)*DIM + (t & 7)*32;
      const float* zr = zrow + (t & 7)*32;
      double s = 0.0;
      #pragma unroll
      for (int d = 0; d < 32; ++d) s = fma((double)zr[d], (double)cr[d], s);
      s += __shfl_xor(s, 4, 8);
      s += __shfl_xor(s, 2, 8);
      s += __shfl_xor(s, 1, 8);
      if ((t & 7) == 0) {
        const int code = ch*32 + (t >> 3);
        const double dd = cn2[code] - 2.0*s;
        if (dd < best) { best = dd; bidx = code; }
      }
    }
    __syncthreads();
    if ((t & 7) == 0) { bls[t >> 3] = best; bis[t >> 3] = bidx; }
    __syncthreads();
    if (t == 0) {
      double bb = bls[0]; int ii = bis[0];
      for (int q = 1; q < 32; ++q)
        if (bls[q] < bb || (bls[q] == bb && bis[q] < ii)) { bb = bls[q]; ii = bis[q]; }
      idx_out[row] = (float)ii;
    }
    __syncthreads();
  }
}

// Gather z_q, write z_q_st, accumulate loss (f64)
__global__ __launch_bounds__(256) void vq_gather(const float* __restrict__ z,
                                                 const float* __restrict__ cb,
                                                 const float* __restrict__ idxf,
                                                 float* __restrict__ zq,
                                                 double* __restrict__ loss_acc, int N) {
  const int t = threadIdx.x, wid = t >> 6, lane = t & 63;
  double ls = 0.0;
  for (int row = blockIdx.x*4 + wid; row < N; row += GB*4) {
    const int idx = (int)idxf[row];
    const f32x4 q  = ((const f32x4*)cb)[(size_t)idx*64 + lane];
    const f32x4 zz = ((const f32x4*)z)[(size_t)row*64 + lane];
    ((f32x4*)zq)[(size_t)row*64 + lane] = q;
    const double dx = (double)q[0] - (double)zz[0];
    const double dy = (double)q[1] - (double)zz[1];
    const double dz2 = (double)q[2] - (double)zz[2];
    const double dw = (double)q[3] - (double)zz[3];
    ls += dx*dx + dy*dy + dz2*dz2 + dw*dw;
  }
  #pragma unroll
  for (int off = 32; off; off >>= 1) ls += __shfl_down(ls, off, 64);
  __shared__ double wsum[4];
  if (lane == 0) wsum[wid] = ls;
  __syncthreads();
  if (t == 0) atomicAdd(loss_acc, wsum[0] + wsum[1] + wsum[2] + wsum[3]);
}

__global__ void vq_finalize(const double* __restrict__ loss_acc,
                            float* __restrict__ out, double inv) {
  const float l = (float)(loss_acc[0] * inv);
  out[0] = l;
  out[1] = l;
}

extern "C" void kernel_launch(void* const* d_in, const int* in_sizes, int n_in,
                              void* d_out, int out_size, void* d_ws, size_t ws_size,
                              hipStream_t stream) {
  const float* z  = (const float*)d_in[0];
  const float* cb = (const float*)d_in[1];
  const int N = in_sizes[0] / DIM;   // 100352
  const int K = in_sizes[1] / DIM;   // 1024
  (void)K;

  float* out     = (float*)d_out;
  float* zq_out  = out + 2;
  float* idx_out = out + 2 + (size_t)N * DIM;

  // ws layout: loss_acc | cn2(8KB) | cnf(4KB) | cbh(512KB) | cbl(512KB)
  double* loss_acc = (double*)d_ws;
  double* cn2      = (double*)((char*)d_ws + 64);
  float*  cnf      = (float*)((char*)d_ws + 64 + 8192);
  ushort* cbh      = (ushort*)((char*)d_ws + 64 + 8192 + 4096);
  ushort* cbl      = (ushort*)((char*)d_ws + 64 + 8192 + 4096 + 524288);

  hipMemsetAsync(d_ws, 0, 64, stream);
  vq_cnorm<<<1024, 64, 0, stream>>>(cb, cn2, cnf, cbh, cbl);
  vq_mfma2<<<N / BM2, NT2, 0, stream>>>(z, cbh, cbl, cnf, idx_out);
  vq_recheck<<<RB, 256, 0, stream>>>(z, cb, cn2, idx_out, N);
  vq_gather<<<GB, 256, 0, stream>>>(z, cb, idx_out, zq_out, loss_acc, N);
  vq_finalize<<<1, 1, 0, stream>>>(loss_acc, out, 1.0 / ((double)N * (double)DIM));
}